// Round 2
// baseline (1252.972 us; speedup 1.0000x reference)
//
#include <hip/hip_runtime.h>
#include <hip/hip_bf16.h>
#include <cstdint>

// Problem: B=8, N=1024, T=32, F=64.  256 independent attention problems of (N=1024, F=64).
// out[b,n,t,f] = relu( ((adj ⊙ softmax(X Xᵀ/8)·(1/8)) X) θᵀ )[n,f]  per (b,t), X row n = x[b,n,t,:].
// All I/O fp32. Internally: split-bf16 (hi+lo) MFMA for QKᵀ (fp32-accurate scores),
// plain bf16 MFMA for PV and the θ epilogue.
#define NN 1024
#define NF 64
#define ROWSTRIDE 2048   // NT*NF: elements between consecutive n for fixed (b,t)

typedef __attribute__((ext_vector_type(8))) short bf16x8;   // 8 bf16 = 4 VGPRs (MFMA A/B frag)
typedef __attribute__((ext_vector_type(4))) float f32x4;    // MFMA C/D frag
typedef unsigned short u16;

__device__ __forceinline__ f32x4 mfma_bf16(bf16x8 a, bf16x8 b, f32x4 c) {
    return __builtin_amdgcn_mfma_f32_16x16x32_bf16(a, b, c, 0, 0, 0);
}
__device__ __forceinline__ float bf16_to_f32(u16 h) {
    unsigned int u = ((unsigned int)h) << 16;
    return __builtin_bit_cast(float, u);
}
__device__ __forceinline__ u16 f32_to_bf16(float f) {
    __hip_bfloat16 h = __float2bfloat16(f);   // RNE
    return __builtin_bit_cast(u16, h);
}
__device__ __forceinline__ void split1(float f, u16& h, u16& l) {
    h = f32_to_bf16(f);
    l = f32_to_bf16(f - bf16_to_f32(h));
}

// MFMA 16x16x32 layouts (HW-verified per guide):
//   A-frag: A[m = lane&15][k = (lane>>4)*8 + r], r=0..7  (8 contiguous bf16)
//   B-frag: B[k = (lane>>4)*8 + r][n = lane&15]
//   C/D  :  D[row = (lane>>4)*4 + reg][col = lane&15]

__launch_bounds__(256, 2)
__global__ void attn_gcn_kernel(const float* __restrict__ x,
                                const float* __restrict__ adj,
                                const float* __restrict__ theta,
                                float* __restrict__ out)
{
    // Xkh/Xkl: 64 keys x 64 f (hi/lo bf16), 16B-chunk XOR swizzle: phys chunk = (f>>3)^(j&7)
    // Xv:      64 f x 64 keys (hi bf16, transposed), phys chunk = (j>>3)^(f&7)
    // Pb:      per-wave P/agg staging: 64 rows x 72 u16 (stride 72 -> 16B-aligned b128 reads)
    __shared__ __align__(16) u16 Xkh[64 * 64];    // 8192 B
    __shared__ __align__(16) u16 Xkl[64 * 64];    // 8192 B
    __shared__ __align__(16) u16 Xv [64 * 64];    // 8192 B
    __shared__ __align__(16) u16 Pb [4 * 64 * 72];// 36864 B   (total 61440 B -> 2 WG/CU)

    const int tid  = threadIdx.x;
    const int w    = tid >> 6;
    const int lane = tid & 63;
    const int l16  = lane & 15;
    const int q    = lane >> 4;

    const int blk = blockIdx.x;
    const int p   = blk >> 2;       // 0..255  (= b*32 + t)
    const int qb  = blk & 3;        // Q-block of 256 rows
    const int b   = p >> 5;
    const int t   = p & 31;

    const float* xb = x + (size_t)b * NN * ROWSTRIDE + (size_t)t * NF;  // + n*ROWSTRIDE for row n
    const int    i0 = qb * 256 + w * 64;                                // this wave's first Q row

    u16* Ps = Pb + w * 4608;   // 64 rows x 72 u16, per-wave private

    // ---- persistent Q fragments (split hi/lo): 4 strips x 2 k-chunks
    bf16x8 aqh[4][2], aql[4][2];
#pragma unroll
    for (int s = 0; s < 4; ++s)
#pragma unroll
        for (int kc = 0; kc < 2; ++kc) {
            const float* qp = xb + (size_t)(i0 + s * 16 + l16) * ROWSTRIDE + kc * 32 + q * 8;
            float4 v0 = *(const float4*)qp;
            float4 v1 = *(const float4*)(qp + 4);
            float vv[8] = {v0.x, v0.y, v0.z, v0.w, v1.x, v1.y, v1.z, v1.w};
            union { u16 h[8]; bf16x8 v; } H, L;
#pragma unroll
            for (int r = 0; r < 8; ++r) split1(vv[r], H.h[r], L.h[r]);
            aqh[s][kc] = H.v;
            aql[s][kc] = L.v;
        }

    const f32x4 zero4 = {0.f, 0.f, 0.f, 0.f};
    f32x4 acc[4][4];
#pragma unroll
    for (int s = 0; s < 4; ++s)
#pragma unroll
        for (int ft = 0; ft < 4; ++ft) acc[s][ft] = zero4;
    float dp[4][4] = {};   // softmax denominator partials, row = q*4+r of strip s

    const float SC = 0.125f * 1.44269504088896340736f;  // exp(S/8) = exp2(S*SC); max-free (S/8 < ~20)

#pragma unroll 1
    for (int kb = 0; kb < 16; ++kb) {
        const int j0 = kb * 64;

        // ---- stage X K-tile (64 keys x 64 f fp32 -> hi/lo bf16), coalesced float4 reads
#pragma unroll
        for (int pp = 0; pp < 4; ++pp) {
            const int j  = (tid >> 4) + pp * 16;
            const int f0 = (tid & 15) * 4;
            float4 v = *(const float4*)(xb + (size_t)(j0 + j) * ROWSTRIDE + f0);
            union { u16 h[4]; ushort4 v4; } H, L;
            split1(v.x, H.h[0], L.h[0]);
            split1(v.y, H.h[1], L.h[1]);
            split1(v.z, H.h[2], L.h[2]);
            split1(v.w, H.h[3], L.h[3]);
            const int base = j * 64 + ((((f0 >> 3) ^ (j & 7))) << 3) + (f0 & 7);
            *(ushort4*)&Xkh[base] = H.v4;
            *(ushort4*)&Xkl[base] = L.v4;
        }
        __syncthreads();   // barrier A: staging visible; all waves past prev PV

        // ---- build Xv = hi(X) transposed (f-major); balanced-bank scalar reads, b128 writes
        {
            const int f = tid & 63;
#pragma unroll
            for (int c = 0; c < 2; ++c) {
                const int jc = (w << 1) | c;   // 0..7
                union { u16 h[8]; uint4 v; } pk;
#pragma unroll
                for (int r = 0; r < 8; ++r)
                    pk.h[r] = Xkh[(jc * 8 + r) * 64 + (((f >> 3) ^ r) << 3) + (f & 7)];
                *(uint4*)&Xv[f * 64 + ((jc ^ (f & 7)) << 3)] = pk.v;
            }
        }

        // ---- QKᵀ (split: hh + hl + lh) -> exp -> ×adj -> bf16 P into per-wave LDS
#pragma unroll
        for (int kt = 0; kt < 4; ++kt) {
            const int j16  = kt * 16 + l16;
            const int base = j16 * 64;
            const int sw   = j16 & 7;
            bf16x8 bh0 = *(const bf16x8*)&Xkh[base + (((0 + q) ^ sw) << 3)];
            bf16x8 bh1 = *(const bf16x8*)&Xkh[base + (((4 + q) ^ sw) << 3)];
            bf16x8 bl0 = *(const bf16x8*)&Xkl[base + (((0 + q) ^ sw) << 3)];
            bf16x8 bl1 = *(const bf16x8*)&Xkl[base + (((4 + q) ^ sw) << 3)];
            f32x4 S[4];
#pragma unroll
            for (int s = 0; s < 4; ++s) {
                f32x4 z = zero4;
                z = mfma_bf16(aqh[s][0], bh0, z);
                z = mfma_bf16(aqh[s][1], bh1, z);
                z = mfma_bf16(aql[s][0], bh0, z);
                z = mfma_bf16(aql[s][1], bh1, z);
                z = mfma_bf16(aqh[s][0], bl0, z);
                z = mfma_bf16(aqh[s][1], bl1, z);
                S[s] = z;
            }
#pragma unroll
            for (int s = 0; s < 4; ++s) {
#pragma unroll
                for (int r = 0; r < 4; ++r) {
                    float e = exp2f(S[s][r] * SC);
                    dp[s][r] += e;                                    // denominator: pre-adj
                    float av = adj[(size_t)(i0 + s * 16 + q * 4 + r) * NN + j0 + kt * 16 + l16];
                    Ps[(s * 16 + q * 4 + r) * 72 + kt * 16 + l16] = f32_to_bf16(e * av);
                }
            }
        }
        __syncthreads();   // barrier B: Xv + P complete

        // ---- PV: acc[s][ft] += P[s] · V
#pragma unroll
        for (int jc = 0; jc < 2; ++jc) {
            bf16x8 ap[4];
#pragma unroll
            for (int s = 0; s < 4; ++s)
                ap[s] = *(const bf16x8*)&Ps[(s * 16 + l16) * 72 + jc * 32 + q * 8];
#pragma unroll
            for (int ft = 0; ft < 4; ++ft) {
                const int f = ft * 16 + l16;
                bf16x8 vv = *(const bf16x8*)&Xv[f * 64 + ((((jc * 4 + q)) ^ (f & 7)) << 3)];
#pragma unroll
                for (int s = 0; s < 4; ++s)
                    acc[s][ft] = mfma_bf16(ap[s], vv, acc[s][ft]);
            }
        }
    }

    // ---- reduce denominators across the 16-lane column groups
    float inv8d[4][4];
#pragma unroll
    for (int s = 0; s < 4; ++s)
#pragma unroll
        for (int r = 0; r < 4; ++r) {
            float v = dp[s][r];
            v += __shfl_xor(v, 1);
            v += __shfl_xor(v, 2);
            v += __shfl_xor(v, 4);
            v += __shfl_xor(v, 8);
            inv8d[s][r] = 1.0f / (8.0f * v);    // extra 1/sqrt(F) from the GCN forward
        }

    // ---- epilogue: out = relu( (acc/(8d)) @ thetaᵀ ), via MFMA with LDS layout round-trip
#pragma unroll
    for (int s = 0; s < 4; ++s)
#pragma unroll
        for (int ft = 0; ft < 4; ++ft)
#pragma unroll
            for (int r = 0; r < 4; ++r)
                Ps[(s * 16 + q * 4 + r) * 72 + ft * 16 + l16] =
                    f32_to_bf16(acc[s][ft][r] * inv8d[s][r]);
    __syncthreads();   // drain LDS writes before cross-lane reads (cheap, once)

    bf16x8 th[2][4];   // B[k=f_in][n=f_out] = theta[f_out][f_in]  (theta is (out,in) row-major)
#pragma unroll
    for (int kc = 0; kc < 2; ++kc)
#pragma unroll
        for (int ft = 0; ft < 4; ++ft) {
            const float* tp = theta + (ft * 16 + l16) * 64 + kc * 32 + q * 8;
            float4 v0 = *(const float4*)tp;
            float4 v1 = *(const float4*)(tp + 4);
            float vv[8] = {v0.x, v0.y, v0.z, v0.w, v1.x, v1.y, v1.z, v1.w};
            union { u16 h[8]; bf16x8 v; } H;
#pragma unroll
            for (int r = 0; r < 8; ++r) H.h[r] = f32_to_bf16(vv[r]);
            th[kc][ft] = H.v;
        }

    float* ob = out + (size_t)b * NN * ROWSTRIDE + (size_t)t * NF;
#pragma unroll
    for (int s = 0; s < 4; ++s) {
        bf16x8 ag0 = *(const bf16x8*)&Ps[(s * 16 + l16) * 72 + 0  + q * 8];
        bf16x8 ag1 = *(const bf16x8*)&Ps[(s * 16 + l16) * 72 + 32 + q * 8];
        f32x4 o[4];
#pragma unroll
        for (int ft = 0; ft < 4; ++ft) {
            f32x4 z = zero4;
            z = mfma_bf16(ag0, th[0][ft], z);
            z = mfma_bf16(ag1, th[1][ft], z);
            o[ft] = z;
        }
#pragma unroll
        for (int ft = 0; ft < 4; ++ft)
#pragma unroll
            for (int r = 0; r < 4; ++r) {
                float v = o[ft][r];
                v = v > 0.f ? v : 0.f;
                ob[(size_t)(i0 + s * 16 + q * 4 + r) * ROWSTRIDE + ft * 16 + l16] = v;
            }
    }
}

extern "C" void kernel_launch(void* const* d_in, const int* in_sizes, int n_in,
                              void* d_out, int out_size, void* d_ws, size_t ws_size,
                              hipStream_t stream) {
    const float* x     = (const float*)d_in[0];   // (8,1024,32,64) fp32
    const float* adj   = (const float*)d_in[1];   // (1024,1024)   fp32
    const float* theta = (const float*)d_in[2];   // (64,64)       fp32
    float* o = (float*)d_out;                     // (8,1024,32,64) fp32
    // 256 (b,t) problems x 4 Q-blocks of 256 rows; 256 threads = 4 waves x 64 Q-rows each
    attn_gcn_kernel<<<dim3(1024), dim3(256), 0, stream>>>(x, adj, theta, o);
}

// Round 3
// 397.849 us; speedup vs baseline: 3.1494x; 3.1494x over previous
//
#include <hip/hip_runtime.h>
#include <hip/hip_bf16.h>
#include <cstdint>

// B=8, N=1024, T=32, F=64.  256 independent attention problems of (N=1024, F=64).
// out = relu( ((adj ⊙ softmax(X Xᵀ/8)) X / 8) θᵀ ) per (b,t); X row n = x[b,n,t,:].
// fp32 I/O. QKᵀ uses asymmetric split-bf16: S = q_hi·(k_hi+k_lo); PV and θ in plain bf16.
#define NN 1024
#define ROWSTRIDE 2048   // NT*NF

typedef __attribute__((ext_vector_type(8))) short bf16x8;
typedef __attribute__((ext_vector_type(4))) float f32x4;
typedef unsigned short u16;

__device__ __forceinline__ f32x4 mfma_bf16(bf16x8 a, bf16x8 b, f32x4 c) {
    return __builtin_amdgcn_mfma_f32_16x16x32_bf16(a, b, c, 0, 0, 0);
}
__device__ __forceinline__ float bf16_to_f32(u16 h) {
    unsigned int u = ((unsigned int)h) << 16;
    return __builtin_bit_cast(float, u);
}
__device__ __forceinline__ u16 f32_to_bf16(float f) {
    __hip_bfloat16 h = __float2bfloat16(f);   // RNE
    return __builtin_bit_cast(u16, h);
}
__device__ __forceinline__ void split1(float f, u16& h, u16& l) {
    h = f32_to_bf16(f);
    l = f32_to_bf16(f - bf16_to_f32(h));
}
__device__ __forceinline__ float ldadj(const float* p, int i) { return p[i]; }
__device__ __forceinline__ float ldadj(const u16* p, int i)   { return bf16_to_f32(p[i]); }

__global__ void cvt_adj_kernel(const float* __restrict__ a, u16* __restrict__ o) {
    int i = (blockIdx.x * 256 + threadIdx.x) * 4;
    float4 v = *(const float4*)(a + i);
    ushort4 h;
    h.x = f32_to_bf16(v.x); h.y = f32_to_bf16(v.y);
    h.z = f32_to_bf16(v.z); h.w = f32_to_bf16(v.w);
    *(ushort4*)(o + i) = h;
}

// MFMA 16x16x32 layouts (HW-verified):
//   A: A[m=lane&15][k=(lane>>4)*8+r]   B: B[k=(lane>>4)*8+r][n=lane&15]
//   C/D: D[row=(lane>>4)*4+reg][col=lane&15]

template <typename AT>
__launch_bounds__(512, 4)
__global__ void attn_gcn_kernel(const float* __restrict__ x,
                                const AT*   __restrict__ adj,
                                const float* __restrict__ theta,
                                float* __restrict__ out)
{
    // Xkh/Xkl: 64 keys x 64 f (hi/lo bf16), 16B-chunk swizzle: phys chunk = (f>>3)^(j&7)
    // Xv:      64 f x 64 keys (hi, transposed), phys chunk = (j>>3)^(f&7)
    // Pb:      per-wave P/agg staging: 32 rows x 72 u16
    __shared__ __align__(16) u16 Xkh[64 * 64];     // 8192 B
    __shared__ __align__(16) u16 Xkl[64 * 64];     // 8192 B
    __shared__ __align__(16) u16 Xv [64 * 64];     // 8192 B
    __shared__ __align__(16) u16 Pb [8 * 32 * 72]; // 36864 B  (total 61440 -> 2 WG/CU)

    const int tid  = threadIdx.x;
    const int w    = tid >> 6;        // wave 0..7
    const int lane = tid & 63;
    const int l16  = lane & 15;
    const int q    = lane >> 4;

    const int blk = blockIdx.x;
    const int p   = blk & 255;        // problem (b*32+t); qb-major for adj L2 locality
    const int qb  = blk >> 8;         // Q-block of 256 rows
    const int b   = p >> 5;
    const int t   = p & 31;

    const float* xb = x + (size_t)b * NN * ROWSTRIDE + (size_t)t * 64;
    const int    i0 = qb * 256 + w * 32;     // this wave's first Q row (32 rows)

    u16* Ps = Pb + w * (32 * 72);            // wave-private

    // ---- persistent Q hi fragments: 2 strips x 2 k-chunks (16 VGPRs)
    bf16x8 aqh[2][2];
#pragma unroll
    for (int s = 0; s < 2; ++s)
#pragma unroll
        for (int kc = 0; kc < 2; ++kc) {
            const float* qp = xb + (size_t)(i0 + s * 16 + l16) * ROWSTRIDE + kc * 32 + q * 8;
            float4 v0 = *(const float4*)qp;
            float4 v1 = *(const float4*)(qp + 4);
            float vv[8] = {v0.x, v0.y, v0.z, v0.w, v1.x, v1.y, v1.z, v1.w};
            union { u16 h[8]; bf16x8 v; } H;
#pragma unroll
            for (int r = 0; r < 8; ++r) H.h[r] = f32_to_bf16(vv[r]);
            aqh[s][kc] = H.v;
        }

    const f32x4 zero4 = {0.f, 0.f, 0.f, 0.f};
    f32x4 acc[2][4];
#pragma unroll
    for (int s = 0; s < 2; ++s)
#pragma unroll
        for (int ft = 0; ft < 4; ++ft) acc[s][ft] = zero4;
    float dp[2][4] = {};

    const float SC = 0.125f * 1.44269504088896340736f;   // exp(S/8)=exp2(S*SC); max-free safe

#pragma unroll 1
    for (int kb = 0; kb < 16; ++kb) {
        const int j0 = kb * 64;

        // ---- stage K-tile: 512 thr, each (j=tid>>3, fc=tid&7): 32B global -> hi/lo 16B chunks
        {
            const int j  = tid >> 3;
            const int fc = tid & 7;
            const float* gp = xb + (size_t)(j0 + j) * ROWSTRIDE + fc * 8;
            float4 v0 = *(const float4*)gp;
            float4 v1 = *(const float4*)(gp + 4);
            float vv[8] = {v0.x, v0.y, v0.z, v0.w, v1.x, v1.y, v1.z, v1.w};
            union { u16 h[8]; uint4 u; } H, L;
#pragma unroll
            for (int r = 0; r < 8; ++r) split1(vv[r], H.h[r], L.h[r]);
            const int base = j * 64 + ((fc ^ (j & 7)) << 3);
            *(uint4*)&Xkh[base] = H.u;
            *(uint4*)&Xkl[base] = L.u;
        }
        __syncthreads();   // A: tile staged; prior-iter Xv reads all done (pre-A)

        // ---- build Xv = hi(X)ᵀ: thread (f=tid&63, jc=tid>>6): 8 scalar reads, 1 b128 write
        {
            const int f  = tid & 63;
            const int jc = tid >> 6;
            union { u16 h[8]; uint4 u; } pk;
#pragma unroll
            for (int r = 0; r < 8; ++r)
                pk.h[r] = Xkh[(jc * 8 + r) * 64 + (((f >> 3) ^ r) << 3) + (f & 7)];
            *(uint4*)&Xv[f * 64 + ((jc ^ (f & 7)) << 3)] = pk.u;
        }

        // ---- QKᵀ (hh + hl) -> exp -> ×adj -> bf16 P (wave-private LDS)
#pragma unroll
        for (int kt = 0; kt < 4; ++kt) {
            const int j16  = kt * 16 + l16;
            const int base = j16 * 64;
            const int sw   = j16 & 7;
            bf16x8 bh0 = *(const bf16x8*)&Xkh[base + (((0 + q) ^ sw) << 3)];
            bf16x8 bh1 = *(const bf16x8*)&Xkh[base + (((4 + q) ^ sw) << 3)];
            bf16x8 bl0 = *(const bf16x8*)&Xkl[base + (((0 + q) ^ sw) << 3)];
            bf16x8 bl1 = *(const bf16x8*)&Xkl[base + (((4 + q) ^ sw) << 3)];
            f32x4 S[2];
#pragma unroll
            for (int s = 0; s < 2; ++s) {
                f32x4 z = zero4;
                z = mfma_bf16(aqh[s][0], bh0, z);
                z = mfma_bf16(aqh[s][1], bh1, z);
                z = mfma_bf16(aqh[s][0], bl0, z);
                z = mfma_bf16(aqh[s][1], bl1, z);
                S[s] = z;
            }
#pragma unroll
            for (int s = 0; s < 2; ++s)
#pragma unroll
                for (int r = 0; r < 4; ++r) {
                    float e = exp2f(S[s][r] * SC);
                    dp[s][r] += e;                       // denom: pre-adjacency
                    float av = ldadj(adj, (i0 + s * 16 + q * 4 + r) * NN + j0 + kt * 16 + l16);
                    Ps[(s * 16 + q * 4 + r) * 72 + kt * 16 + l16] = f32_to_bf16(e * av);
                }
        }
        __syncthreads();   // B: Xv complete (P is wave-private; lgkmcnt orders it)

        // ---- PV: acc[s][ft] += P[s] · V
#pragma unroll
        for (int jc = 0; jc < 2; ++jc) {
            bf16x8 ap[2];
#pragma unroll
            for (int s = 0; s < 2; ++s)
                ap[s] = *(const bf16x8*)&Ps[(s * 16 + l16) * 72 + jc * 32 + q * 8];
#pragma unroll
            for (int ft = 0; ft < 4; ++ft) {
                const int f = ft * 16 + l16;
                bf16x8 vv = *(const bf16x8*)&Xv[f * 64 + ((((jc * 4 + q)) ^ (f & 7)) << 3)];
#pragma unroll
                for (int s = 0; s < 2; ++s)
                    acc[s][ft] = mfma_bf16(ap[s], vv, acc[s][ft]);
            }
        }
    }

    // ---- denominator reduce over the 16-lane column group
    float inv8d[2][4];
#pragma unroll
    for (int s = 0; s < 2; ++s)
#pragma unroll
        for (int r = 0; r < 4; ++r) {
            float v = dp[s][r];
            v += __shfl_xor(v, 1);
            v += __shfl_xor(v, 2);
            v += __shfl_xor(v, 4);
            v += __shfl_xor(v, 8);
            inv8d[s][r] = 1.0f / (8.0f * v);   // extra 1/sqrt(F) from GCN forward
        }

    // ---- epilogue: out = relu( (acc/(8d)) @ thetaᵀ ) via wave-private LDS round-trip
#pragma unroll
    for (int s = 0; s < 2; ++s)
#pragma unroll
        for (int ft = 0; ft < 4; ++ft)
#pragma unroll
            for (int r = 0; r < 4; ++r)
                Ps[(s * 16 + q * 4 + r) * 72 + ft * 16 + l16] =
                    f32_to_bf16(acc[s][ft][r] * inv8d[s][r]);

    bf16x8 th[2][4];   // B[k=f_in][n=f_out] = theta[f_out][f_in]
#pragma unroll
    for (int kc = 0; kc < 2; ++kc)
#pragma unroll
        for (int ft = 0; ft < 4; ++ft) {
            const float* tp = theta + (ft * 16 + l16) * 64 + kc * 32 + q * 8;
            float4 v0 = *(const float4*)tp;
            float4 v1 = *(const float4*)(tp + 4);
            float vv[8] = {v0.x, v0.y, v0.z, v0.w, v1.x, v1.y, v1.z, v1.w};
            union { u16 h[8]; bf16x8 v; } H;
#pragma unroll
            for (int r = 0; r < 8; ++r) H.h[r] = f32_to_bf16(vv[r]);
            th[kc][ft] = H.v;
        }

    float* ob = out + (size_t)b * NN * ROWSTRIDE + (size_t)t * 64;
#pragma unroll
    for (int s = 0; s < 2; ++s) {
        bf16x8 ag0 = *(const bf16x8*)&Ps[(s * 16 + l16) * 72 + 0  + q * 8];
        bf16x8 ag1 = *(const bf16x8*)&Ps[(s * 16 + l16) * 72 + 32 + q * 8];
#pragma unroll
        for (int ft = 0; ft < 4; ++ft) {
            f32x4 z = zero4;
            z = mfma_bf16(ag0, th[0][ft], z);
            z = mfma_bf16(ag1, th[1][ft], z);
#pragma unroll
            for (int r = 0; r < 4; ++r) {
                float v = z[r];
                v = v > 0.f ? v : 0.f;
                ob[(size_t)(i0 + s * 16 + q * 4 + r) * ROWSTRIDE + ft * 16 + l16] = v;
            }
        }
    }
}

extern "C" void kernel_launch(void* const* d_in, const int* in_sizes, int n_in,
                              void* d_out, int out_size, void* d_ws, size_t ws_size,
                              hipStream_t stream) {
    const float* x     = (const float*)d_in[0];   // (8,1024,32,64) fp32
    const float* adj   = (const float*)d_in[1];   // (1024,1024)   fp32
    const float* theta = (const float*)d_in[2];   // (64,64)       fp32
    float* o = (float*)d_out;                     // (8,1024,32,64) fp32

    const size_t adj_bytes = (size_t)NN * NN * sizeof(u16);
    if (ws_size >= adj_bytes) {
        u16* adjb = (u16*)d_ws;
        cvt_adj_kernel<<<dim3(NN * NN / (256 * 4)), dim3(256), 0, stream>>>(adj, adjb);
        attn_gcn_kernel<u16><<<dim3(1024), dim3(512), 0, stream>>>(x, adjb, theta, o);
    } else {
        attn_gcn_kernel<float><<<dim3(1024), dim3(512), 0, stream>>>(x, adj, theta, o);
    }
}

// Round 4
// 346.715 us; speedup vs baseline: 3.6138x; 1.1475x over previous
//
#include <hip/hip_runtime.h>
#include <hip/hip_bf16.h>
#include <cstdint>

// B=8, N=1024, T=32, F=64.  256 independent attention problems of (N=1024, F=64).
// out = relu( ((adj ⊙ softmax(X Xᵀ/8)) X / 8) θᵀ ) per (b,t); X row n = x[b,n,t,:].
// fp32 I/O. Round-4 structure: compute Sᵀ (A=keys, B=queries) so the MFMA C/D layout
// gives 4 consecutive keys per lane -> ushort4 adj loads, b64 P stores, float4 out stores.
// QKᵀ split-bf16 asymmetric: S = (k_hi+k_lo)·q_hi; PV and θ in plain bf16.
#define NN 1024
#define ROWSTRIDE 2048   // NT*NF

typedef __attribute__((ext_vector_type(8))) short bf16x8;
typedef __attribute__((ext_vector_type(4))) float f32x4;
typedef unsigned short u16;

__device__ __forceinline__ f32x4 mfma_bf16(bf16x8 a, bf16x8 b, f32x4 c) {
    return __builtin_amdgcn_mfma_f32_16x16x32_bf16(a, b, c, 0, 0, 0);
}
__device__ __forceinline__ float bf16_to_f32(u16 h) {
    unsigned int u = ((unsigned int)h) << 16;
    return __builtin_bit_cast(float, u);
}
__device__ __forceinline__ u16 f32_to_bf16(float f) {
    __hip_bfloat16 h = __float2bfloat16(f);   // RNE
    return __builtin_bit_cast(u16, h);
}
__device__ __forceinline__ void split1(float f, u16& h, u16& l) {
    h = f32_to_bf16(f);
    l = f32_to_bf16(f - bf16_to_f32(h));
}
__device__ __forceinline__ void ldadj4(const u16* p, int i, float* o) {
    ushort4 v = *(const ushort4*)(p + i);
    o[0] = bf16_to_f32(v.x); o[1] = bf16_to_f32(v.y);
    o[2] = bf16_to_f32(v.z); o[3] = bf16_to_f32(v.w);
}
__device__ __forceinline__ void ldadj4(const float* p, int i, float* o) {
    float4 v = *(const float4*)(p + i);
    o[0] = v.x; o[1] = v.y; o[2] = v.z; o[3] = v.w;
}

__global__ void cvt_adj_kernel(const float* __restrict__ a, u16* __restrict__ o) {
    int i = (blockIdx.x * 256 + threadIdx.x) * 4;
    float4 v = *(const float4*)(a + i);
    ushort4 h;
    h.x = f32_to_bf16(v.x); h.y = f32_to_bf16(v.y);
    h.z = f32_to_bf16(v.z); h.w = f32_to_bf16(v.w);
    *(ushort4*)(o + i) = h;
}

// MFMA 16x16x32 layouts (HW-verified):
//   A: A[m=lane&15][k=(lane>>4)*8+r]   B: B[k=(lane>>4)*8+r][n=lane&15]
//   C/D: D[row=(lane>>4)*4+reg][col=lane&15]

template <typename AT>
__launch_bounds__(512, 4)
__global__ void attn_gcn_kernel(const float* __restrict__ x,
                                const AT*   __restrict__ adj,
                                const float* __restrict__ theta,
                                float* __restrict__ out)
{
    // Xkh/Xkl: 64 keys x 64 f (hi/lo bf16), 16B-chunk swizzle: phys chunk = (fc)^(j&7)
    // Xv:      64 f x 64 keys (hi, transposed), phys chunk = (mc)^(f&7)
    // Pb:      per-wave Pᵀ/aggᵀ staging: 32 n-rows x 72 u16 (b64/b128-aligned)
    __shared__ __align__(16) u16 Xkh[64 * 64];     // 8192 B
    __shared__ __align__(16) u16 Xkl[64 * 64];     // 8192 B
    __shared__ __align__(16) u16 Xv [64 * 64];     // 8192 B
    __shared__ __align__(16) u16 Pb [8 * 32 * 72]; // 36864 B  (total 61440 -> 2 WG/CU)

    const int tid  = threadIdx.x;
    const int w    = tid >> 6;
    const int lane = tid & 63;
    const int l16  = lane & 15;
    const int q    = lane >> 4;

    const int blk = blockIdx.x;
    const int p   = blk & 255;        // problem (b*32+t); qb-major for adj L2 reuse
    const int qb  = blk >> 8;
    const int b   = p >> 5;
    const int t   = p & 31;

    const float* xb = x + (size_t)b * NN * ROWSTRIDE + (size_t)t * 64;
    const int    i0 = qb * 256 + w * 32;      // wave's 32 query rows

    u16* Ps = Pb + w * (32 * 72);             // wave-private

    // ---- Q B-frags (hi only): B[k=kc*32+q*8+r][n=l16] = Q[i0+s*16+l16][kc*32+q*8+r]
    bf16x8 bq[2][2];
#pragma unroll
    for (int s = 0; s < 2; ++s)
#pragma unroll
        for (int kc = 0; kc < 2; ++kc) {
            const float* qp = xb + (size_t)(i0 + s * 16 + l16) * ROWSTRIDE + kc * 32 + q * 8;
            float4 v0 = *(const float4*)qp;
            float4 v1 = *(const float4*)(qp + 4);
            float vv[8] = {v0.x, v0.y, v0.z, v0.w, v1.x, v1.y, v1.z, v1.w};
            union { u16 h[8]; bf16x8 v; } H;
#pragma unroll
            for (int r = 0; r < 8; ++r) H.h[r] = f32_to_bf16(vv[r]);
            bq[s][kc] = H.v;
        }

    const f32x4 zero4 = {0.f, 0.f, 0.f, 0.f};
    f32x4 acc[2][4];              // aggᵀ[f-tile][..]: row=f in tile ft, col=n in strip s
#pragma unroll
    for (int s = 0; s < 2; ++s)
#pragma unroll
        for (int ft = 0; ft < 4; ++ft) acc[s][ft] = zero4;
    float dp[2] = {0.f, 0.f};     // denom partials; n = i0+s*16+l16 is lane-fixed

    const float SC = 0.125f * 1.44269504088896340736f;   // exp(S/8)=exp2(S*SC); max-free safe

    // staging role: key row j, f-chunk fc (8 floats)
    const int js = tid >> 3, fcs = tid & 7;
    const float* gbase = xb + (size_t)js * ROWSTRIDE + fcs * 8;
    float4 g0 = *(const float4*)gbase;            // prefetch kb=0
    float4 g1 = *(const float4*)(gbase + 4);

#pragma unroll 1
    for (int kb = 0; kb < 16; ++kb) {
        const int j0 = kb * 64;

        // ---- write staged X-tile regs -> hi/lo LDS (swizzled 16B chunks)
        {
            float vv[8] = {g0.x, g0.y, g0.z, g0.w, g1.x, g1.y, g1.z, g1.w};
            union { u16 h[8]; uint4 u; } H, L;
#pragma unroll
            for (int r = 0; r < 8; ++r) split1(vv[r], H.h[r], L.h[r]);
            const int base = js * 64 + ((fcs ^ (js & 7)) << 3);
            *(uint4*)&Xkh[base] = H.u;
            *(uint4*)&Xkl[base] = L.u;
        }
        __syncthreads();   // A: tile staged; all waves past prior PV (Xv safe to rebuild)

        // ---- build Xv = hi(X)ᵀ: thread (f=tid&63, mc=tid>>6)
        {
            const int f  = tid & 63;
            const int mc = tid >> 6;
            union { u16 h[8]; uint4 u; } pk;
#pragma unroll
            for (int r = 0; r < 8; ++r)
                pk.h[r] = Xkh[(mc * 8 + r) * 64 + (((f >> 3) ^ r) << 3) + (f & 7)];
            *(uint4*)&Xv[f * 64 + ((mc ^ (f & 7)) << 3)] = pk.u;
        }

        // ---- Sᵀ = K·Qᵀ (hh+hl) -> exp -> ×adj (ushort4) -> Pᵀ b64 stores (wave-private)
#pragma unroll
        for (int kt = 0; kt < 4; ++kt) {
            const int j16  = kt * 16 + l16;     // key row within tile
            const int base = j16 * 64;
            const int sw   = j16 & 7;
            bf16x8 akh0 = *(const bf16x8*)&Xkh[base + (((0 + q) ^ sw) << 3)];
            bf16x8 akh1 = *(const bf16x8*)&Xkh[base + (((4 + q) ^ sw) << 3)];
            bf16x8 akl0 = *(const bf16x8*)&Xkl[base + (((0 + q) ^ sw) << 3)];
            bf16x8 akl1 = *(const bf16x8*)&Xkl[base + (((4 + q) ^ sw) << 3)];
#pragma unroll
            for (int s = 0; s < 2; ++s) {
                const int n = i0 + s * 16 + l16;
                float av[4];
                ldadj4(adj, n * NN + j0 + kt * 16 + q * 4, av);   // 4 consecutive keys
                f32x4 z = zero4;
                z = mfma_bf16(akh0, bq[s][0], z);
                z = mfma_bf16(akh1, bq[s][1], z);
                z = mfma_bf16(akl0, bq[s][0], z);
                z = mfma_bf16(akl1, bq[s][1], z);
                // z[r] = Sᵀ[m = j0+kt*16+q*4+r][n]
                union { u16 h[4]; ushort4 u; } P4;
                float es = 0.f;
#pragma unroll
                for (int r = 0; r < 4; ++r) {
                    float e = exp2f(z[r] * SC);
                    es += e;
                    P4.h[r] = f32_to_bf16(e * av[r]);
                }
                dp[s] += es;
                *(ushort4*)&Ps[(s * 16 + l16) * 72 + kt * 16 + q * 4] = P4.u;
            }
        }
        __syncthreads();   // B: Xv complete (Pᵀ is wave-private; lgkm orders it)

        // ---- prefetch next X-tile into regs (overlaps PV MFMAs)
        if (kb < 15) {
            const float* gp = gbase + (size_t)(j0 + 64) * ROWSTRIDE;
            g0 = *(const float4*)gp;
            g1 = *(const float4*)(gp + 4);
        }

        // ---- PV: aggᵀ[f][n] += Xv(A) · Pᵀ(B)
#pragma unroll
        for (int kc = 0; kc < 2; ++kc) {
            bf16x8 bp[2];
#pragma unroll
            for (int s = 0; s < 2; ++s)
                bp[s] = *(const bf16x8*)&Ps[(s * 16 + l16) * 72 + kc * 32 + q * 8];
#pragma unroll
            for (int ft = 0; ft < 4; ++ft) {
                const int fr = ft * 16 + l16;
                bf16x8 axv = *(const bf16x8*)&Xv[fr * 64 + (((kc * 4 + q) ^ (fr & 7)) << 3)];
#pragma unroll
                for (int s = 0; s < 2; ++s)
                    acc[s][ft] = mfma_bf16(axv, bp[s], acc[s][ft]);
            }
        }
    }

    // ---- denominator reduce: lanes {l16 + 16q} share n
    float inv8d[2];
#pragma unroll
    for (int s = 0; s < 2; ++s) {
        float v = dp[s];
        v += __shfl_xor(v, 16);
        v += __shfl_xor(v, 32);
        inv8d[s] = 1.0f / (8.0f * v);   // extra 1/sqrt(F) from GCN forward
    }

    // ---- epilogue: outᵀ = θ(A) · aggᵀ(B), agg scaled by 1/(8d); LDS round-trip (wave-private)
#pragma unroll
    for (int s = 0; s < 2; ++s)
#pragma unroll
        for (int ft = 0; ft < 4; ++ft) {
            union { u16 h[4]; ushort4 u; } A4;
#pragma unroll
            for (int r = 0; r < 4; ++r)
                A4.h[r] = f32_to_bf16(acc[s][ft][r] * inv8d[s]);
            *(ushort4*)&Ps[(s * 16 + l16) * 72 + ft * 16 + q * 4] = A4.u;
        }

    bf16x8 th[4][2];   // A[row=fo in tile fot][k=kc*32+q*8+r] = θ[fot*16+l16][...]
#pragma unroll
    for (int fot = 0; fot < 4; ++fot)
#pragma unroll
        for (int kc = 0; kc < 2; ++kc) {
            const float* tp = theta + (fot * 16 + l16) * 64 + kc * 32 + q * 8;
            float4 v0 = *(const float4*)tp;
            float4 v1 = *(const float4*)(tp + 4);
            float vv[8] = {v0.x, v0.y, v0.z, v0.w, v1.x, v1.y, v1.z, v1.w};
            union { u16 h[8]; bf16x8 v; } H;
#pragma unroll
            for (int r = 0; r < 8; ++r) H.h[r] = f32_to_bf16(vv[r]);
            th[fot][kc] = H.v;
        }

    float* ob = out + (size_t)b * NN * ROWSTRIDE + (size_t)t * 64;
#pragma unroll
    for (int s = 0; s < 2; ++s) {
        bf16x8 bg0 = *(const bf16x8*)&Ps[(s * 16 + l16) * 72 + 0  + q * 8];
        bf16x8 bg1 = *(const bf16x8*)&Ps[(s * 16 + l16) * 72 + 32 + q * 8];
        const int n = i0 + s * 16 + l16;
#pragma unroll
        for (int fot = 0; fot < 4; ++fot) {
            f32x4 z = zero4;
            z = mfma_bf16(th[fot][0], bg0, z);
            z = mfma_bf16(th[fot][1], bg1, z);
            // z[r] = out[n][fo = fot*16 + q*4 + r]
            float4 o4;
            o4.x = z[0] > 0.f ? z[0] : 0.f;
            o4.y = z[1] > 0.f ? z[1] : 0.f;
            o4.z = z[2] > 0.f ? z[2] : 0.f;
            o4.w = z[3] > 0.f ? z[3] : 0.f;
            *(float4*)(ob + (size_t)n * ROWSTRIDE + fot * 16 + q * 4) = o4;
        }
    }
}

extern "C" void kernel_launch(void* const* d_in, const int* in_sizes, int n_in,
                              void* d_out, int out_size, void* d_ws, size_t ws_size,
                              hipStream_t stream) {
    const float* x     = (const float*)d_in[0];   // (8,1024,32,64) fp32
    const float* adj   = (const float*)d_in[1];   // (1024,1024)   fp32
    const float* theta = (const float*)d_in[2];   // (64,64)       fp32
    float* o = (float*)d_out;                     // (8,1024,32,64) fp32

    const size_t adj_bytes = (size_t)NN * NN * sizeof(u16);
    if (ws_size >= adj_bytes) {
        u16* adjb = (u16*)d_ws;
        cvt_adj_kernel<<<dim3(NN * NN / (256 * 4)), dim3(256), 0, stream>>>(adj, adjb);
        attn_gcn_kernel<u16><<<dim3(1024), dim3(512), 0, stream>>>(x, adjb, theta, o);
    } else {
        attn_gcn_kernel<float><<<dim3(1024), dim3(512), 0, stream>>>(x, adj, theta, o);
    }
}

// Round 5
// 324.412 us; speedup vs baseline: 3.8623x; 1.0687x over previous
//
#include <hip/hip_runtime.h>
#include <hip/hip_bf16.h>
#include <cstdint>

// B=8, N=1024, T=32, F=64.  256 independent attention problems of (N=1024, F=64).
// out = relu( ((adj ⊙ softmax(X Xᵀ/8)) X / 8) θᵀ ) per (b,t); X row n = x[b,n,t,:].
// fp32 I/O. Round-5: plain-bf16 QKᵀ with EXACT fp32 diagonal substitution (the only
// error-sensitive score); P stays in registers (cross-lane shuffle C/D->B-frag, no LDS);
// LDS = 16 KB (Xkh + Xv only).
#define NN 1024
#define ROWSTRIDE 2048   // NT*NF

typedef __attribute__((ext_vector_type(8))) short bf16x8;
typedef __attribute__((ext_vector_type(4))) float f32x4;
typedef unsigned short u16;

__device__ __forceinline__ f32x4 mfma_bf16(bf16x8 a, bf16x8 b, f32x4 c) {
    return __builtin_amdgcn_mfma_f32_16x16x32_bf16(a, b, c, 0, 0, 0);
}
__device__ __forceinline__ float bf16_to_f32(u16 h) {
    unsigned int u = ((unsigned int)h) << 16;
    return __builtin_bit_cast(float, u);
}
__device__ __forceinline__ u16 f32_to_bf16(float f) {
    __hip_bfloat16 h = __float2bfloat16(f);   // RNE
    return __builtin_bit_cast(u16, h);
}
__device__ __forceinline__ uint32_t pack2(float a, float b) {
    return (uint32_t)f32_to_bf16(a) | ((uint32_t)f32_to_bf16(b) << 16);
}
__device__ __forceinline__ void ldadj4(const u16* p, int i, float* o) {
    ushort4 v = *(const ushort4*)(p + i);
    o[0] = bf16_to_f32(v.x); o[1] = bf16_to_f32(v.y);
    o[2] = bf16_to_f32(v.z); o[3] = bf16_to_f32(v.w);
}
__device__ __forceinline__ void ldadj4(const float* p, int i, float* o) {
    float4 v = *(const float4*)(p + i);
    o[0] = v.x; o[1] = v.y; o[2] = v.z; o[3] = v.w;
}

__global__ void cvt_adj_kernel(const float* __restrict__ a, u16* __restrict__ o) {
    int i = (blockIdx.x * 256 + threadIdx.x) * 4;
    float4 v = *(const float4*)(a + i);
    ushort4 h;
    h.x = f32_to_bf16(v.x); h.y = f32_to_bf16(v.y);
    h.z = f32_to_bf16(v.z); h.w = f32_to_bf16(v.w);
    *(ushort4*)(o + i) = h;
}

// MFMA 16x16x32 layouts (HW-verified):
//   A: A[m=lane&15][k=(lane>>4)*8+r]   B: B[k=(lane>>4)*8+r][n=lane&15]
//   C/D: D[row=(lane>>4)*4+reg][col=lane&15]
//
// C/D -> B-frag transform (keys axis): lane(l16,q') B-frag u32 j of chunk kc comes from
// pk[t=2kc+(q'>>1)] of lane l16+16*(2(q'&1) + (j>>1)), pair d(j&1).
__device__ __forceinline__ bf16x8 shufB(const uint32_t* d0, const uint32_t* d1,
                                        int kc, int srcA, int srcB, bool qhi) {
    uint32_t l0A = (uint32_t)__shfl((int)d0[2*kc],     srcA);
    uint32_t l1A = (uint32_t)__shfl((int)d1[2*kc],     srcA);
    uint32_t l0B = (uint32_t)__shfl((int)d0[2*kc],     srcB);
    uint32_t l1B = (uint32_t)__shfl((int)d1[2*kc],     srcB);
    uint32_t h0A = (uint32_t)__shfl((int)d0[2*kc + 1], srcA);
    uint32_t h1A = (uint32_t)__shfl((int)d1[2*kc + 1], srcA);
    uint32_t h0B = (uint32_t)__shfl((int)d0[2*kc + 1], srcB);
    uint32_t h1B = (uint32_t)__shfl((int)d1[2*kc + 1], srcB);
    union { uint32_t u[4]; bf16x8 v; } R;
    R.u[0] = qhi ? h0A : l0A;
    R.u[1] = qhi ? h1A : l1A;
    R.u[2] = qhi ? h0B : l0B;
    R.u[3] = qhi ? h1B : l1B;
    return R.v;
}

template <typename AT>
__launch_bounds__(512, 4)
__global__ void attn_gcn_kernel(const float* __restrict__ x,
                                const AT*   __restrict__ adj,
                                const float* __restrict__ theta,
                                float* __restrict__ out)
{
    // Xkh: 64 keys x 64 f (hi bf16), 16B-chunk swizzle: phys chunk = fc^(j&7)
    // Xv:  64 f x 64 keys (hi, transposed), phys chunk = mc^(f&7)
    __shared__ __align__(16) u16 Xkh[64 * 64];   // 8192 B
    __shared__ __align__(16) u16 Xv [64 * 64];   // 8192 B   (total 16 KB)

    const int tid  = threadIdx.x;
    const int lane = tid & 63;
    const int l16  = lane & 15;
    const int q    = lane >> 4;
    const bool qhi = (q >> 1) != 0;
    const int srcA = l16 + 32 * (q & 1);
    const int srcB = srcA + 16;

    const int blk = blockIdx.x;
    const int p   = blk & 255;        // problem (b*32+t); qb-major for adj L2 reuse
    const int qb  = blk >> 8;
    const int b   = p >> 5;
    const int t   = p & 31;

    const float* xb = x + (size_t)b * NN * ROWSTRIDE + (size_t)t * 64;
    const int    i0 = qb * 256 + (tid >> 6) * 32;   // wave's 32 query rows

    // ---- Q B-frags (hi) + exact row norms (fp32)
    bf16x8 bq[2][2];
    float  nrm[2] = {0.f, 0.f};
#pragma unroll
    for (int s = 0; s < 2; ++s) {
#pragma unroll
        for (int kc = 0; kc < 2; ++kc) {
            const float* qp = xb + (size_t)(i0 + s * 16 + l16) * ROWSTRIDE + kc * 32 + q * 8;
            float4 v0 = *(const float4*)qp;
            float4 v1 = *(const float4*)(qp + 4);
            float vv[8] = {v0.x, v0.y, v0.z, v0.w, v1.x, v1.y, v1.z, v1.w};
            union { u16 h[8]; bf16x8 v; } H;
#pragma unroll
            for (int r = 0; r < 8; ++r) {
                nrm[s] += vv[r] * vv[r];
                H.h[r] = f32_to_bf16(vv[r]);
            }
            bq[s][kc] = H.v;
        }
        // reduce over the 4 q-lanes holding this row's 64 elements
        nrm[s] += __shfl_xor(nrm[s], 16);
        nrm[s] += __shfl_xor(nrm[s], 32);
    }
    // diagonal location: key n lands in k-tile kbd[s], sub-tile ktd[s],
    // C/D lane q == l16>>2, element r == l16&3   (i0+16s is a multiple of 16)
    const int kbd0 = (i0) >> 6,        ktd0 = ((i0) >> 4) & 3;
    const int kbd1 = (i0 + 16) >> 6,   ktd1 = ((i0 + 16) >> 4) & 3;
    const bool dlane = (q == (l16 >> 2));
    const int  dr    = l16 & 3;

    // per-lane adj row base (n = i0 + 16s + l16)
    const AT* adjr0 = adj + (size_t)(i0 + l16) * NN;
    const AT* adjr1 = adj + (size_t)(i0 + 16 + l16) * NN;

    const f32x4 zero4 = {0.f, 0.f, 0.f, 0.f};
    f32x4 acc[2][4];
#pragma unroll
    for (int s = 0; s < 2; ++s)
#pragma unroll
        for (int ft = 0; ft < 4; ++ft) acc[s][ft] = zero4;
    float dp[2] = {0.f, 0.f};

    const float SC = 0.125f * 1.44269504088896340736f;   // exp(S/8)=exp2(S*SC); max-free safe

    // staging role: key row js, f-chunk fcs (8 floats)
    const int js = tid >> 3, fcs = tid & 7;
    const float* gbase = xb + (size_t)js * ROWSTRIDE + fcs * 8;
    float4 g0 = *(const float4*)gbase;            // prefetch kb=0
    float4 g1 = *(const float4*)(gbase + 4);

#pragma unroll 1
    for (int kb = 0; kb < 16; ++kb) {
        const int j0 = kb * 64;

        // ---- write staged X-tile (hi bf16) -> LDS swizzled 16B chunks
        {
            float vv[8] = {g0.x, g0.y, g0.z, g0.w, g1.x, g1.y, g1.z, g1.w};
            union { u16 h[8]; uint4 u; } H;
#pragma unroll
            for (int r = 0; r < 8; ++r) H.h[r] = f32_to_bf16(vv[r]);
            *(uint4*)&Xkh[js * 64 + ((fcs ^ (js & 7)) << 3)] = H.u;
        }
        __syncthreads();   // A: tile staged; all waves past prior PV (Xv safe to rebuild)

        // ---- build Xv = hi(X)ᵀ: thread (f=tid&63, mc=tid>>6)
        {
            const int f  = tid & 63;
            const int mc = tid >> 6;
            union { u16 h[8]; uint4 u; } pkv;
#pragma unroll
            for (int r = 0; r < 8; ++r)
                pkv.h[r] = Xkh[(mc * 8 + r) * 64 + (((f >> 3) ^ r) << 3) + (f & 7)];
            *(uint4*)&Xv[f * 64 + ((mc ^ (f & 7)) << 3)] = pkv.u;
        }

        // ---- Sᵀ = K·Qᵀ (bf16) -> exact-diag fix -> exp -> ×adj -> packed P in registers
        uint32_t pk0[2][4], pk1[2][4];   // [s][kt]: keys 16kt+4q+{0,1} / {2,3}
#pragma unroll
        for (int kt = 0; kt < 4; ++kt) {
            const int j16  = kt * 16 + l16;     // key row within tile
            const int base = j16 * 64;
            const int sw   = j16 & 7;
            bf16x8 akh0 = *(const bf16x8*)&Xkh[base + (((0 + q) ^ sw) << 3)];
            bf16x8 akh1 = *(const bf16x8*)&Xkh[base + (((4 + q) ^ sw) << 3)];
#pragma unroll
            for (int s = 0; s < 2; ++s) {
                f32x4 z = zero4;
                z = mfma_bf16(akh0, bq[s][0], z);
                z = mfma_bf16(akh1, bq[s][1], z);
                // exact diagonal substitution
                const bool isd = (s == 0) ? (kb == kbd0 && kt == ktd0)
                                          : (kb == kbd1 && kt == ktd1);
                if (isd && dlane) {
#pragma unroll
                    for (int r = 0; r < 4; ++r)
                        if (r == dr) z[r] = nrm[s];
                }
                float av[4];
                ldadj4((s == 0) ? adjr0 : adjr1, j0 + kt * 16 + q * 4, av);
                float e0 = exp2f(z[0] * SC), e1 = exp2f(z[1] * SC);
                float e2 = exp2f(z[2] * SC), e3 = exp2f(z[3] * SC);
                dp[s] += (e0 + e1) + (e2 + e3);
                pk0[s][kt] = pack2(e0 * av[0], e1 * av[1]);
                pk1[s][kt] = pack2(e2 * av[2], e3 * av[3]);
            }
        }
        __syncthreads();   // B: Xv complete; all QK reads of Xkh done (safe to restage)

        // ---- prefetch next X-tile into regs (overlaps PV MFMAs)
        if (kb < 15) {
            const float* gp = gbase + (size_t)(j0 + 64) * ROWSTRIDE;
            g0 = *(const float4*)gp;
            g1 = *(const float4*)(gp + 4);
        }

        // ---- PV: aggᵀ[f][n] += Xv(A) · Pᵀ(B);  Pᵀ B-frags via cross-lane shuffles
#pragma unroll
        for (int kc = 0; kc < 2; ++kc) {
            bf16x8 bp0 = shufB(pk0[0], pk1[0], kc, srcA, srcB, qhi);
            bf16x8 bp1 = shufB(pk0[1], pk1[1], kc, srcA, srcB, qhi);
#pragma unroll
            for (int ft = 0; ft < 4; ++ft) {
                const int fr = ft * 16 + l16;
                bf16x8 axv = *(const bf16x8*)&Xv[fr * 64 + (((kc * 4 + q) ^ (fr & 7)) << 3)];
                acc[0][ft] = mfma_bf16(axv, bp0, acc[0][ft]);
                acc[1][ft] = mfma_bf16(axv, bp1, acc[1][ft]);
            }
        }
    }

    // ---- denominator reduce: lanes {l16 + 16q} share n
    float inv8d[2];
#pragma unroll
    for (int s = 0; s < 2; ++s) {
        float v = dp[s];
        v += __shfl_xor(v, 16);
        v += __shfl_xor(v, 32);
        inv8d[s] = 1.0f / (8.0f * v);   // extra 1/sqrt(F) from GCN forward
    }

    // ---- epilogue: outᵀ = θ(A) · aggᵀ(B); agg C/D -> B-frag via the same shuffle
    bf16x8 th[4][2];   // A[m=l16 (fo in tile fot)][k=kc2*32+q*8+r] = θ[fot*16+l16][...]
#pragma unroll
    for (int fot = 0; fot < 4; ++fot)
#pragma unroll
        for (int kc = 0; kc < 2; ++kc) {
            const float* tp = theta + (fot * 16 + l16) * 64 + kc * 32 + q * 8;
            float4 v0 = *(const float4*)tp;
            float4 v1 = *(const float4*)(tp + 4);
            float vv[8] = {v0.x, v0.y, v0.z, v0.w, v1.x, v1.y, v1.z, v1.w};
            union { u16 h[8]; bf16x8 v; } H;
#pragma unroll
            for (int r = 0; r < 8; ++r) H.h[r] = f32_to_bf16(vv[r]);
            th[fot][kc] = H.v;
        }

    float* ob = out + (size_t)b * NN * ROWSTRIDE + (size_t)t * 64;
#pragma unroll
    for (int s = 0; s < 2; ++s) {
        uint32_t ed0[4], ed1[4];   // packed agg/(8d): f = 16ft+4q+{0,1}/{2,3}
#pragma unroll
        for (int ft = 0; ft < 4; ++ft) {
            ed0[ft] = pack2(acc[s][ft][0] * inv8d[s], acc[s][ft][1] * inv8d[s]);
            ed1[ft] = pack2(acc[s][ft][2] * inv8d[s], acc[s][ft][3] * inv8d[s]);
        }
        const int n = i0 + s * 16 + l16;
#pragma unroll
        for (int kc = 0; kc < 2; ++kc) {
            bf16x8 bg = shufB(ed0, ed1, kc, srcA, srcB, qhi);
#pragma unroll
            for (int fot = 0; fot < 4; ++fot) {
                // accumulate over both kc chunks: do kc=0 into temp, kc=1 adds
                // (restructured: compute per fot with both chunks below)
                (void)fot;
            }
            // store bg for second pass via regs
            if (kc == 0) {
#pragma unroll
                for (int fot = 0; fot < 4; ++fot) {
                    f32x4 z = zero4;
                    z = mfma_bf16(th[fot][0], bg, z);
                    // stash partial in acc[s][fot] (reuse, no longer needed)
                    acc[s][fot] = z;
                }
            } else {
#pragma unroll
                for (int fot = 0; fot < 4; ++fot) {
                    f32x4 z = mfma_bf16(th[fot][1], bg, acc[s][fot]);
                    float4 o4;
                    o4.x = z[0] > 0.f ? z[0] : 0.f;
                    o4.y = z[1] > 0.f ? z[1] : 0.f;
                    o4.z = z[2] > 0.f ? z[2] : 0.f;
                    o4.w = z[3] > 0.f ? z[3] : 0.f;
                    *(float4*)(ob + (size_t)n * ROWSTRIDE + fot * 16 + q * 4) = o4;
                }
            }
        }
    }
}

extern "C" void kernel_launch(void* const* d_in, const int* in_sizes, int n_in,
                              void* d_out, int out_size, void* d_ws, size_t ws_size,
                              hipStream_t stream) {
    const float* x     = (const float*)d_in[0];   // (8,1024,32,64) fp32
    const float* adj   = (const float*)d_in[1];   // (1024,1024)   fp32
    const float* theta = (const float*)d_in[2];   // (64,64)       fp32
    float* o = (float*)d_out;                     // (8,1024,32,64) fp32

    const size_t adj_bytes = (size_t)NN * NN * sizeof(u16);
    if (ws_size >= adj_bytes) {
        u16* adjb = (u16*)d_ws;
        cvt_adj_kernel<<<dim3(NN * NN / (256 * 4)), dim3(256), 0, stream>>>(adj, adjb);
        attn_gcn_kernel<u16><<<dim3(1024), dim3(512), 0, stream>>>(x, adjb, theta, o);
    } else {
        attn_gcn_kernel<float><<<dim3(1024), dim3(512), 0, stream>>>(x, adj, theta, o);
    }
}